// Round 13
// baseline (224.528 us; speedup 1.0000x reference)
//
#include <hip/hip_runtime.h>
#include <stdint.h>

#define F8MAX 448.0f
#define QEPS 1e-12f
#define SCL_ONE 0x7F7F7F7F   // E8M0 exponent 127 => 2^0 = 1.0 per byte
#define AXB 4096             // amax partial blocks

typedef float floatx16 __attribute__((ext_vector_type(16)));
typedef int   intx4    __attribute__((ext_vector_type(4)));
typedef int   intx8    __attribute__((ext_vector_type(8)));

// ---------------- pass 1: dual per-block amax partials (x and w in one kernel) ----------------
__global__ __launch_bounds__(256) void amax_partial_xw(
    const float* __restrict__ x, int nx4,
    const float* __restrict__ w, int nw4,
    float* __restrict__ px, float* __restrict__ pw)
{
    const float4* x4 = (const float4*)x;
    const float4* w4 = (const float4*)w;
    int tid = blockIdx.x * 256 + threadIdx.x;
    int stride = gridDim.x * 256;
    float mx = 0.f, mw = 0.f;
    for (int i = tid; i < nx4; i += stride) {
        float4 v = x4[i];
        mx = fmaxf(mx, fmaxf(fmaxf(fabsf(v.x), fabsf(v.y)), fmaxf(fabsf(v.z), fabsf(v.w))));
    }
    for (int i = tid; i < nw4; i += stride) {
        float4 v = w4[i];
        mw = fmaxf(mw, fmaxf(fmaxf(fabsf(v.x), fabsf(v.y)), fmaxf(fabsf(v.z), fabsf(v.w))));
    }
    #pragma unroll
    for (int off = 32; off > 0; off >>= 1) {
        mx = fmaxf(mx, __shfl_xor(mx, off, 64));
        mw = fmaxf(mw, __shfl_xor(mw, off, 64));
    }
    __shared__ float smx[4], smw[4];
    if ((threadIdx.x & 63) == 0) { smx[threadIdx.x >> 6] = mx; smw[threadIdx.x >> 6] = mw; }
    __syncthreads();
    if (threadIdx.x == 0) {
        px[blockIdx.x] = fmaxf(fmaxf(smx[0], smx[1]), fmaxf(smx[2], smx[3]));
        pw[blockIdx.x] = fmaxf(fmaxf(smw[0], smw[1]), fmaxf(smw[2], smw[3]));
    }
}

// ---------------- pass 2: quantize w into scrambled layout (32 quarter-panels) ----------------
// Same structure as round 12's quant (known good), w-only.
__global__ __launch_bounds__(512) void quant_w(
    const float* __restrict__ w, uint8_t* __restrict__ w8,
    const float* __restrict__ pw, int nkt, int K)
{
    __shared__ uint8_t lds[32768];

    float m = 0.f;
    for (int i = threadIdx.x; i < AXB; i += 512) m = fmaxf(m, pw[i]);
    #pragma unroll
    for (int off = 32; off > 0; off >>= 1) m = fmaxf(m, __shfl_xor(m, off, 64));
    __shared__ float red[8];
    if ((threadIdx.x & 63) == 0) red[threadIdx.x >> 6] = m;
    __syncthreads();
    float amax = red[0];
    #pragma unroll
    for (int i = 1; i < 8; i++) amax = fmaxf(amax, red[i]);

    float scale = fmaxf(amax, QEPS) / F8MAX;
    float rs = 1.0f / scale;

    int hp = blockIdx.x;                       // quarter-panel
    int p = hp >> 2, q = hp & 3;
    int wave = threadIdx.x >> 6, lane = threadIdx.x & 63;
    int K4 = K >> 2;

    const float4* s4 = (const float4*)w + (size_t)hp * 32 * K4;
    uint32_t key = (lane >> 2) & 7;
    uint32_t lbase = ((uint32_t)(lane >> 4) * 2048) + (((lane >> 2) & 3) * 512) + ((lane & 3) * 4);
    #pragma unroll
    for (int rr = 0; rr < 4; rr++) {
        int r = rr * 8 + wave;
        const float4* rowp = s4 + (size_t)r * K4;
        #pragma unroll
        for (int j = 0; j < 4; j++) {
            float4 f = rowp[j * 64 + lane];
            int wd = 0;
            wd = __builtin_amdgcn_cvt_pk_fp8_f32(f.x * rs, f.y * rs, wd, false);
            wd = __builtin_amdgcn_cvt_pk_fp8_f32(f.z * rs, f.w * rs, wd, true);
            uint32_t a = (uint32_t)j * 8192 + lbase + (uint32_t)r * 16;
            a ^= (key << 4);
            *(int*)(lds + a) = wd;
        }
    }
    __syncthreads();

    uint8_t* outb = w8 + (size_t)(p * nkt) * 8192 + q * 512;
    int l32 = lane & 31, chi = lane >> 5;
    #pragma unroll
    for (int it = 0; it < 4; it++) {
        int c = it * 16 + wave * 2 + chi;
        int kt = c >> 2, hpc = c & 3;
        uint32_t k2 = (uint32_t)(((kt & 1) << 2) | hpc);
        uint32_t a = (uint32_t)c * 512 + (((uint32_t)l32 * 16) ^ (k2 << 4));
        int4 v = *(const int4*)(lds + a);
        *(int4*)(outb + (size_t)kt * 8192 + hpc * 2048 + l32 * 16) = v;
    }
}

// ---------------- pass 3: FUSED quant-x + MX-fp8 GEMM, 256^2 tile ----------------
// A-path: per kt, 512 threads load the fp32 A-tile coalesced (thread t: row t>>4 (+32/round),
// 16B at col (t&15)*4), convert with rs_x, ds_write_b32 into fragment-layout LDS with XOR
// swizzle key (t>>2)&3 == hl*2+pc (write 2-way free; read applies same key per piece).
// B-path: pre-quantized w8 via global_load_lds (linear, no swizzle).
// 2 LDS buffers; per kt: issue loads(kt+1) -> compute(kt) -> vmcnt(0) -> cvt+write -> barrier.
__global__ __launch_bounds__(512, 1) void gemm_fused(
    const float* __restrict__ x, const uint8_t* __restrict__ B8,
    float* __restrict__ C, const float* __restrict__ bias,
    const float* __restrict__ px, const float* __restrict__ pw,
    int N, int K, int nkt, int nbn, int nbm)
{
    __shared__ uint8_t lsA[2 * 16384];
    __shared__ uint8_t lsB[2 * 16384];

    int wave = threadIdx.x >> 6, lane = threadIdx.x & 63;
    int wr = wave >> 2, wc = wave & 3;        // 2(M) x 4(N)
    int hl = lane >> 5, l31 = lane & 31;

    // ---- scales: every block redundantly reduces the partial arrays (deterministic) ----
    float m1 = 0.f, m2 = 0.f;
    for (int i = threadIdx.x; i < AXB; i += 512) {
        m1 = fmaxf(m1, px[i]);
        m2 = fmaxf(m2, pw[i]);
    }
    #pragma unroll
    for (int off = 32; off > 0; off >>= 1) {
        m1 = fmaxf(m1, __shfl_xor(m1, off, 64));
        m2 = fmaxf(m2, __shfl_xor(m2, off, 64));
    }
    __shared__ float redx[8], redw[8];
    if (lane == 0) { redx[wave] = m1; redw[wave] = m2; }
    __syncthreads();
    float ax = redx[0], aw = redw[0];
    #pragma unroll
    for (int i = 1; i < 8; i++) { ax = fmaxf(ax, redx[i]); aw = fmaxf(aw, redw[i]); }
    float sclx = fmaxf(ax, QEPS) / F8MAX;     // exactly the reference's scale
    float sclw = fmaxf(aw, QEPS) / F8MAX;
    float rsx = 1.0f / sclx;
    float s = sclx * sclw;

    // ---- block mapping: XCD-chunked swizzle, then reverse bm (L3: amax left x-tail hot) ----
    int nwg = gridDim.x;
    int bid = blockIdx.x;
    if ((nwg & 7) == 0) {
        int chunk = nwg >> 3;
        bid = (blockIdx.x & 7) * chunk + (blockIdx.x >> 3);
    }
    int bm = bid / nbn, bn = bid - bm * nbn;
    bm = nbm - 1 - bm;

    // ---- A fp32 load base: thread t covers (row t>>4 + 32*round, col quarter (t&15)*4) ----
    const float* gx = x + (size_t)(bm * 256 + (threadIdx.x >> 4)) * K + (threadIdx.x & 15) * 4;

    // A LDS write: linear = (r>>7)*8192 + h*4096 + pc*2048 + (r&127)*16 + (t&3)*4, ^ key<<4
    uint32_t awbase = (((threadIdx.x >> 3) & 1) * 4096) + (((threadIdx.x >> 2) & 1) * 2048)
                    + ((threadIdx.x & 3) * 4);
    uint32_t wkey = (((uint32_t)threadIdx.x >> 2) & 3) << 4;
    int r_lo = threadIdx.x >> 4;              // 0..31

    // ---- B staging: 16 x 1KB chunks per kt; wave v owns chunks 2v, 2v+1 ----
    int c0 = wave * 2, c1 = wave * 2 + 1;
    const uint8_t* gB0 = B8 + (size_t)(bn * 2 + (c0 >> 3)) * nkt * 8192 + (c0 & 7) * 1024 + lane * 16;
    const uint8_t* gB1 = B8 + (size_t)(bn * 2 + (c1 >> 3)) * nkt * 8192 + (c1 & 7) * 1024 + lane * 16;
    uint32_t lb0 = (uint32_t)c0 * 1024, lb1 = (uint32_t)c1 * 1024;

    // ---- fragment read bases ----
    uint32_t aR = (uint32_t)wr * 8192 + (uint32_t)hl * 4096 + (uint32_t)l31 * 16;
    uint32_t keyA0 = (uint32_t)(hl * 2 + 0) << 4;
    uint32_t keyA1 = (uint32_t)(hl * 2 + 1) << 4;
    uint32_t bR = (uint32_t)(wc >> 1) * 8192 + (uint32_t)hl * 4096 + (uint32_t)(wc & 1) * 1024
                + (uint32_t)l31 * 16;

    floatx16 acc[4][2];
    #pragma unroll
    for (int m = 0; m < 4; m++)
        #pragma unroll
        for (int n = 0; n < 2; n++)
            acc[m][n] = (floatx16)(0.0f);

#define LOADA(KT, F)                                                              \
    {                                                                             \
        const float* ga = gx + (size_t)(KT) * 64;                                 \
        _Pragma("unroll")                                                         \
        for (int k = 0; k < 8; k++)                                               \
            F[k] = *(const float4*)(ga + (size_t)k * 32 * K);                     \
    }

#define LOADB(KT, BO)                                                             \
    __builtin_amdgcn_global_load_lds(                                             \
        (const __attribute__((address_space(1))) void*)(gB0 + (size_t)(KT) * 8192), \
        (__attribute__((address_space(3))) void*)(lsB + (BO) + lb0), 16, 0, 0);   \
    __builtin_amdgcn_global_load_lds(                                             \
        (const __attribute__((address_space(1))) void*)(gB1 + (size_t)(KT) * 8192), \
        (__attribute__((address_space(3))) void*)(lsB + (BO) + lb1), 16, 0, 0)

#define CVTWRITE(F, BO)                                                           \
    {                                                                             \
        _Pragma("unroll")                                                         \
        for (int k = 0; k < 8; k++) {                                             \
            int wd = 0;                                                           \
            wd = __builtin_amdgcn_cvt_pk_fp8_f32(F[k].x * rsx, F[k].y * rsx, wd, false); \
            wd = __builtin_amdgcn_cvt_pk_fp8_f32(F[k].z * rsx, F[k].w * rsx, wd, true);  \
            int r = k * 32 + r_lo;                                                \
            uint32_t a = (((uint32_t)(r >> 7) * 8192 + (uint32_t)(r & 127) * 16 + awbase) ^ wkey); \
            *(int*)(lsA + (BO) + a) = wd;                                         \
        }                                                                         \
    }

#define RDA(M, BO) __builtin_shufflevector(                                        \
        *(const intx4*)(lsA + (BO) + ((aR + (M) * 512) ^ keyA0)),                  \
        *(const intx4*)(lsA + (BO) + ((aR + (M) * 512 + 2048) ^ keyA1)),           \
        0, 1, 2, 3, 4, 5, 6, 7)

#define RDB(Nn, BO) __builtin_shufflevector(                                       \
        *(const intx4*)(lsB + (BO) + (bR + (Nn) * 512)),                           \
        *(const intx4*)(lsB + (BO) + (bR + (Nn) * 512 + 2048)),                    \
        0, 1, 2, 3, 4, 5, 6, 7)

#define MMX(m, n) acc[m][n] = __builtin_amdgcn_mfma_scale_f32_32x32x64_f8f6f4(     \
        af[m], bf[n], acc[m][n], 0, 0, 0, SCL_ONE, 0, SCL_ONE)

    // ---- prologue: stage kt = 0 ----
    {
        float4 f0[8];
        LOADA(0, f0);
        LOADB(0, 0);
        asm volatile("s_waitcnt vmcnt(0)" ::: "memory");
        CVTWRITE(f0, 0);
    }
    __syncthreads();

    for (int kt = 0; kt < nkt; kt++) {
        uint32_t bo = (uint32_t)(kt & 1) * 16384;
        uint32_t bo2 = bo ^ 16384;
        bool pf = (kt + 1 < nkt);
        float4 f[8];

        if (pf) {
            LOADA(kt + 1, f);
            LOADB(kt + 1, bo2);
        }

        intx8 af[4], bf[2];
        af[0] = RDA(0, bo); af[1] = RDA(1, bo);
        bf[0] = RDB(0, bo); bf[1] = RDB(1, bo);
        af[2] = RDA(2, bo); af[3] = RDA(3, bo);

        __builtin_amdgcn_s_setprio(1);
        MMX(0, 0); MMX(0, 1); MMX(1, 0); MMX(1, 1);
        MMX(2, 0); MMX(2, 1); MMX(3, 0); MMX(3, 1);
        __builtin_amdgcn_s_setprio(0);

        if (pf) {
            asm volatile("s_waitcnt vmcnt(0)" ::: "memory");   // A regs + B LDS landed
            CVTWRITE(f, bo2);
        }
        __syncthreads();   // writes to bo2 visible; all reads of bo complete
    }

    // C/D 32x32: col = lane&31, row = (reg&3) + 8*(reg>>2) + 4*(lane>>5)
    #pragma unroll
    for (int m = 0; m < 4; m++) {
        int row0 = bm * 256 + wr * 128 + m * 32 + 4 * hl;
        #pragma unroll
        for (int n = 0; n < 2; n++) {
            int col = bn * 256 + wc * 64 + n * 32 + l31;
            float bv = bias[col];
            #pragma unroll
            for (int reg = 0; reg < 16; reg++) {
                int row = row0 + (reg & 3) + 8 * (reg >> 2);
                __builtin_nontemporal_store(acc[m][n][reg] * s + bv, &C[(size_t)row * N + col]);
            }
        }
    }
#undef LOADA
#undef LOADB
#undef CVTWRITE
#undef RDA
#undef RDB
#undef MMX
}

extern "C" void kernel_launch(void* const* d_in, const int* in_sizes, int n_in,
                              void* d_out, int out_size, void* d_ws, size_t ws_size,
                              hipStream_t stream)
{
    const float* x    = (const float*)d_in[0];
    const float* w    = (const float*)d_in[1];
    const float* bias = (const float*)d_in[2];
    float* out = (float*)d_out;

    int N = in_sizes[2];                 // 1024
    int K = in_sizes[1] / N;             // 1024
    int M = in_sizes[0] / K;             // 65536
    int nx = in_sizes[0];
    int nw = in_sizes[1];
    int nkt = K / 64;                    // 16

    uint8_t* ws = (uint8_t*)d_ws;
    float* px = (float*)(ws + 64);                    // 4096 partials (x)
    float* pw = (float*)(ws + 64 + 16384);            // 4096 partials (w)
    uint8_t* w8 = ws + 65536;                         // N*K scrambled fp8

    amax_partial_xw<<<AXB, 256, 0, stream>>>(x, nx / 4, w, nw / 4, px, pw);
    quant_w<<<N / 32, 512, 0, stream>>>(w, w8, pw, nkt, K);

    int nbm = M / 256, nbn = N / 256;    // 256 x 4 = 1024 blocks
    gemm_fused<<<nbm * nbn, 512, 0, stream>>>(x, w8, out, bias, px, pw, N, K, nkt, nbn, nbm);
}

// Round 14
// 203.495 us; speedup vs baseline: 1.1034x; 1.1034x over previous
//
#include <hip/hip_runtime.h>
#include <stdint.h>

#define F8MAX 448.0f
#define QEPS 1e-12f
#define SCL_ONE 0x7F7F7F7F   // E8M0 exponent 127 => 2^0 = 1.0 per byte
#define AXB 4096             // amax partial blocks

typedef float floatx16 __attribute__((ext_vector_type(16)));
typedef int   intx4    __attribute__((ext_vector_type(4)));
typedef int   intx8    __attribute__((ext_vector_type(8)));

// ---------------- pass 1: dual per-block amax partials (x and w in one kernel) ----------------
__global__ __launch_bounds__(256) void amax_partial_xw(
    const float* __restrict__ x, int nx4,
    const float* __restrict__ w, int nw4,
    float* __restrict__ px, float* __restrict__ pw)
{
    const float4* x4 = (const float4*)x;
    const float4* w4 = (const float4*)w;
    int tid = blockIdx.x * 256 + threadIdx.x;
    int stride = gridDim.x * 256;
    float mx = 0.f, mw = 0.f;
    for (int i = tid; i < nx4; i += stride) {
        float4 v = x4[i];
        mx = fmaxf(mx, fmaxf(fmaxf(fabsf(v.x), fabsf(v.y)), fmaxf(fabsf(v.z), fabsf(v.w))));
    }
    for (int i = tid; i < nw4; i += stride) {
        float4 v = w4[i];
        mw = fmaxf(mw, fmaxf(fmaxf(fabsf(v.x), fabsf(v.y)), fmaxf(fabsf(v.z), fabsf(v.w))));
    }
    #pragma unroll
    for (int off = 32; off > 0; off >>= 1) {
        mx = fmaxf(mx, __shfl_xor(mx, off, 64));
        mw = fmaxf(mw, __shfl_xor(mw, off, 64));
    }
    __shared__ float smx[4], smw[4];
    if ((threadIdx.x & 63) == 0) { smx[threadIdx.x >> 6] = mx; smw[threadIdx.x >> 6] = mw; }
    __syncthreads();
    if (threadIdx.x == 0) {
        px[blockIdx.x] = fmaxf(fmaxf(smx[0], smx[1]), fmaxf(smx[2], smx[3]));
        pw[blockIdx.x] = fmaxf(fmaxf(smw[0], smw[1]), fmaxf(smw[2], smw[3]));
    }
}

// ---------------- pass 2: quant, 32-row quarter-panels, 512 thr, 32KB LDS (100% occ) ----------
// Output layout: tile(p,kt) byte = h*4096 + pc*2048 + r*16 + (k&15), h=(k>>5)&1, pc=(k>>4)&1.
// Quarter q covers r in [q*32, q*32+32) -> 512B runs at chunk(kt,hpc) + q*512.
// LDS image: [16 kt][4 hpc][32 r][16B] = 32KB, XOR-swizzled on byte bits 4..6 with
// key = (lane>>2)&7 (phase A) == ((kt&1)<<2)|hpc (phase B).
__global__ __launch_bounds__(512) void quant_fused(
    const float* __restrict__ x, const float* __restrict__ w,
    uint8_t* __restrict__ x8, uint8_t* __restrict__ w8,
    const float* __restrict__ px, const float* __restrict__ pw,
    unsigned* __restrict__ hdr, int nhx, int nkt, int K)
{
    __shared__ uint8_t lds[32768];

    int bid = blockIdx.x;
    bool isw = (bid < 32);                 // w: 32 quarter-panels (N=1024)
    const float* par = isw ? pw : px;

    // redundant reduce of the 4096-entry partial array (deterministic -> identical everywhere)
    float m = 0.f;
    for (int i = threadIdx.x; i < AXB; i += 512) m = fmaxf(m, par[i]);
    #pragma unroll
    for (int off = 32; off > 0; off >>= 1) m = fmaxf(m, __shfl_xor(m, off, 64));
    __shared__ float red[8];
    if ((threadIdx.x & 63) == 0) red[threadIdx.x >> 6] = m;
    __syncthreads();
    float amax = red[0];
    #pragma unroll
    for (int i = 1; i < 8; i++) amax = fmaxf(amax, red[i]);

    float scale = fmaxf(amax, QEPS) / F8MAX;   // exactly the reference's scale
    float rs = 1.0f / scale;                   // reciprocal-multiply

    if (threadIdx.x == 0) {
        if (bid == 0)  hdr[1] = __float_as_uint(amax);   // amax_w for gemm epilogue
        if (bid == 32) hdr[0] = __float_as_uint(amax);   // amax_x
    }

    int hp = isw ? bid : (nhx - 1 - (bid - 32));   // x back-to-front: L3 reuse after amax
    const float* src = isw ? w : x;
    uint8_t* dst8 = isw ? w8 : x8;
    int p = hp >> 2, q = hp & 3;                   // 128-row panel, quarter

    int wave = threadIdx.x >> 6, lane = threadIdx.x & 63;
    int K4 = K >> 2;

    // ---- phase A: 32 rows -> LDS (coalesced 1KB wave-reads) ----
    const float4* s4 = (const float4*)src + (size_t)hp * 32 * K4;
    uint32_t key = (lane >> 2) & 7;
    uint32_t lbase = ((uint32_t)(lane >> 4) * 2048) + (((lane >> 2) & 3) * 512) + ((lane & 3) * 4);
    #pragma unroll
    for (int rr = 0; rr < 4; rr++) {
        int r = rr * 8 + wave;                 // 0..31
        const float4* rowp = s4 + (size_t)r * K4;
        #pragma unroll
        for (int j = 0; j < 4; j++) {
            float4 f = rowp[j * 64 + lane];    // 1KB contiguous per wave-instr
            int wd = 0;
            wd = __builtin_amdgcn_cvt_pk_fp8_f32(f.x * rs, f.y * rs, wd, false);
            wd = __builtin_amdgcn_cvt_pk_fp8_f32(f.z * rs, f.w * rs, wd, true);
            uint32_t a = (uint32_t)j * 8192 + lbase + (uint32_t)r * 16;
            a ^= (key << 4);
            *(int*)(lds + a) = wd;
        }
    }
    __syncthreads();

    // ---- phase B: LDS -> global, 64 chunks x 512B, 512B contiguous per 32-lane group ----
    uint8_t* outb = dst8 + (size_t)(p * nkt) * 8192 + q * 512;
    int l32 = lane & 31, chi = lane >> 5;
    #pragma unroll
    for (int it = 0; it < 4; it++) {
        int c = it * 16 + wave * 2 + chi;      // chunk 0..63
        int kt = c >> 2, hpc = c & 3;
        uint32_t k2 = (uint32_t)(((kt & 1) << 2) | hpc);
        uint32_t a = (uint32_t)c * 512 + (((uint32_t)l32 * 16) ^ (k2 << 4));
        int4 v = *(const int4*)(lds + a);
        *(int4*)(outb + (size_t)kt * 8192 + hpc * 2048 + l32 * 16) = v;
    }
}

// ---------------- pass 3: MX-scaled fp8 GEMM, 256^2 tile, 4-buffer depth-3 pipeline ------------
// C[M,N] = (A8 . B8^T)*s + bias; 8 waves (2M x 4N), BK=64, 4 LDS buffers (128KB, 1 blk/CU),
// prefetch 3 tiles ahead, counted vmcnt(8) steady-state.
__global__ __launch_bounds__(512, 1) void gemm_fp8_mx(
    const uint8_t* __restrict__ A8, const uint8_t* __restrict__ B8,
    float* __restrict__ C, const float* __restrict__ bias,
    const unsigned* __restrict__ hdr, int N, int nkt, int nbn)
{
    __shared__ uint8_t lsA[4 * 16384];
    __shared__ uint8_t lsB[4 * 16384];

    int nwg = gridDim.x;
    int bid = blockIdx.x;
    if ((nwg & 7) == 0) {
        int chunk = nwg >> 3;
        bid = (blockIdx.x & 7) * chunk + (blockIdx.x >> 3);
    }
    int bm = bid / nbn, bn = bid - bm * nbn;

    int t = threadIdx.x;
    int wave = t >> 6, lane = t & 63;
    int wr = wave >> 2, wc = wave & 3;        // 2(M) x 4(N)
    int hl = lane >> 5, l31 = lane & 31;

    const uint8_t* gsrc0; const uint8_t* gsrc1; const uint8_t* gsrc2; const uint8_t* gsrc3;
    uint32_t ld0, ld1, ld2, ld3;
    bool isA = (wave < 4);
    {
        int c0 = wave * 4;
        #pragma unroll
        for (int p = 0; p < 4; p++) {
            int c = c0 + p;
            const uint8_t* g;
            uint32_t l;
            if (c < 16) {
                int h = c >> 3, sub = c & 7;
                g = A8 + (size_t)(bm * 2 + h) * nkt * 8192 + sub * 1024 + lane * 16;
                l = (uint32_t)c * 1024;
            } else {
                int cc = c - 16, h = cc >> 3, sub = cc & 7;
                g = B8 + (size_t)(bn * 2 + h) * nkt * 8192 + sub * 1024 + lane * 16;
                l = (uint32_t)cc * 1024;
            }
            if (p == 0) { gsrc0 = g; ld0 = l; }
            else if (p == 1) { gsrc1 = g; ld1 = l; }
            else if (p == 2) { gsrc2 = g; ld2 = l; }
            else { gsrc3 = g; ld3 = l; }
        }
    }
    uint8_t* lsbase = isA ? lsA : lsB;

#define ISSUE(GP, LO, KT2, B2)                                                   \
    __builtin_amdgcn_global_load_lds(                                            \
        (const __attribute__((address_space(1))) void*)((GP) + (size_t)(KT2) * 8192), \
        (__attribute__((address_space(3))) void*)(lsbase + (B2) * 16384 + (LO)), \
        16, 0, 0)

    const uint8_t* baseA = lsA + wr * 8192 + hl * 4096 + l31 * 16;
    const uint8_t* baseB = lsB + (wc >> 1) * 8192 + hl * 4096 + (wc & 1) * 1024 + l31 * 16;

    floatx16 acc[4][2];
    #pragma unroll
    for (int m = 0; m < 4; m++)
        #pragma unroll
        for (int n = 0; n < 2; n++)
            acc[m][n] = (floatx16)(0.0f);

#define RD8(BASE, OFF) __builtin_shufflevector(                         \
        *(const intx4*)((BASE) + (OFF)),                                \
        *(const intx4*)((BASE) + (OFF) + 2048), 0, 1, 2, 3, 4, 5, 6, 7)

#define MMX(m, n) acc[m][n] = __builtin_amdgcn_mfma_scale_f32_32x32x64_f8f6f4( \
        af[m], bf[n], acc[m][n], 0, 0, 0, SCL_ONE, 0, SCL_ONE)

    ISSUE(gsrc0, ld0, 0, 0); ISSUE(gsrc1, ld1, 0, 0); ISSUE(gsrc2, ld2, 0, 0); ISSUE(gsrc3, ld3, 0, 0);
    ISSUE(gsrc0, ld0, 1, 1); ISSUE(gsrc1, ld1, 1, 1); ISSUE(gsrc2, ld2, 1, 1); ISSUE(gsrc3, ld3, 1, 1);
    ISSUE(gsrc0, ld0, 2, 2); ISSUE(gsrc1, ld1, 2, 2); ISSUE(gsrc2, ld2, 2, 2); ISSUE(gsrc3, ld3, 2, 2);
    asm volatile("s_waitcnt vmcnt(8)" ::: "memory");   // tile 0 landed; 1,2 in flight
    asm volatile("s_barrier" ::: "memory");

    for (int kt = 0; kt < nkt; kt++) {
        int cur = kt & 3;
        int ib = (cur + 3) & 3;                         // (kt+3) % 4
        const uint8_t* cA = baseA + cur * 16384;
        const uint8_t* cB = baseB + cur * 16384;
        intx8 af[4], bf[2];

        if (kt + 3 < nkt) {
            ISSUE(gsrc0, ld0, kt + 3, ib); ISSUE(gsrc1, ld1, kt + 3, ib);
            ISSUE(gsrc2, ld2, kt + 3, ib); ISSUE(gsrc3, ld3, kt + 3, ib);
        }

        af[0] = RD8(cA, 0);    af[1] = RD8(cA, 512);
        bf[0] = RD8(cB, 0);    bf[1] = RD8(cB, 512);
        af[2] = RD8(cA, 1024); af[3] = RD8(cA, 1536);

        __builtin_amdgcn_s_setprio(1);
        MMX(0, 0); MMX(0, 1); MMX(1, 0); MMX(1, 1);
        MMX(2, 0); MMX(2, 1); MMX(3, 0); MMX(3, 1);
        __builtin_amdgcn_s_setprio(0);

        if (kt + 1 < nkt) {
            if (kt + 4 <= nkt - 1)      asm volatile("s_waitcnt vmcnt(8)" ::: "memory");
            else if (kt + 3 <= nkt - 1) asm volatile("s_waitcnt vmcnt(4)" ::: "memory");
            else                        asm volatile("s_waitcnt vmcnt(0)" ::: "memory");
            asm volatile("s_barrier" ::: "memory");
        }
    }

    float sxv = fmaxf(__uint_as_float(hdr[0]), QEPS) / F8MAX;
    float swv = fmaxf(__uint_as_float(hdr[1]), QEPS) / F8MAX;
    float s = sxv * swv;

    // C/D 32x32: col = lane&31, row = (reg&3) + 8*(reg>>2) + 4*(lane>>5)
    #pragma unroll
    for (int m = 0; m < 4; m++) {
        int row0 = bm * 256 + wr * 128 + m * 32 + 4 * hl;
        #pragma unroll
        for (int n = 0; n < 2; n++) {
            int col = bn * 256 + wc * 64 + n * 32 + l31;
            float bv = bias[col];
            #pragma unroll
            for (int reg = 0; reg < 16; reg++) {
                int row = row0 + (reg & 3) + 8 * (reg >> 2);
                __builtin_nontemporal_store(acc[m][n][reg] * s + bv, &C[(size_t)row * N + col]);
            }
        }
    }
#undef ISSUE
#undef RD8
#undef MMX
}

extern "C" void kernel_launch(void* const* d_in, const int* in_sizes, int n_in,
                              void* d_out, int out_size, void* d_ws, size_t ws_size,
                              hipStream_t stream)
{
    const float* x    = (const float*)d_in[0];
    const float* w    = (const float*)d_in[1];
    const float* bias = (const float*)d_in[2];
    float* out = (float*)d_out;

    int N = in_sizes[2];                 // 1024
    int K = in_sizes[1] / N;             // 1024
    int M = in_sizes[0] / K;             // 65536
    int nx = in_sizes[0];
    int nw = in_sizes[1];
    int nkt = K / 64;                    // 16

    uint8_t* ws = (uint8_t*)d_ws;
    unsigned* hdr = (unsigned*)ws;                    // [0]=amax_x bits, [1]=amax_w bits
    float* px = (float*)(ws + 64);                    // 4096 partials (x)
    float* pw = (float*)(ws + 64 + 16384);            // 4096 partials (w)
    uint8_t* w8 = ws + 65536;
    uint8_t* x8 = ws + 65536 + (size_t)N * K;

    int nhx = M / 32;                    // 2048 quarter-panels of x
    int nhw = N / 32;                    // 32 quarter-panels of w

    amax_partial_xw<<<AXB, 256, 0, stream>>>(x, nx / 4, w, nw / 4, px, pw);
    quant_fused<<<nhw + nhx, 512, 0, stream>>>(x, w, x8, w8, px, pw, hdr, nhx, nkt, K);

    int nbm = M / 256, nbn = N / 256;    // 256 x 4 = 1024 blocks
    gemm_fp8_mx<<<nbm * nbn, 512, 0, stream>>>(x8, w8, out, bias, hdr, N, nkt, nbn);
}